// Round 2
// baseline (63548.749 us; speedup 1.0000x reference)
//
#include <hip/hip_runtime.h>

// ============================================================================
// CustomMultiInputLSTM (B=64, H=512, T=1024, 7 aux inputs) on gfx950.
//
// Round 2 changes vs round 1 (which never launched: out was bit-identical to
// the stub run => ws_size guard returned early and/or coop launch error was
// silently dropped):
//  * NO workspace dependence: weight blobs + recurrent state live in static
//    __device__ globals (~21.4 MB .bss), re-initialized by prep every call.
//  * hipLaunchCooperativeKernel return value CHECKED; fallback plain launch
//    (208 blocks, <=6/CU by LDS => co-resident on 256 CUs).
//
// Design:
//  * Sequential recurrence -> ONE persistent kernel, 1024 steps, 2
//    device-wide barriers/step (monotone-counter barrier, agent scope).
//  * All 26 per-step [64x512]@[512x512] matmuls via v_mfma_f32_16x16x32_f16,
//    split-f16: x ~= x_hi + (1/2048)*x_lo (lo pre-scaled by 2048). 3 MFMAs
//    per fragment pair; fp32 accumulate => ~fp32 accuracy (f16*f16 exact in
//    fp32), needed for 7e-4 absmax over a 1024-step recurrence.
//  * Weights pre-swizzled once per launch into MFMA B-fragment blobs:
//    [mat][kt][ntile16][lane][8] f16 -> one dwordx4 per lane.
//  * Grid = 208 WGs x 256 thr:
//      WG 0..143  : phase A = channel-pair kappa (i-type + c-type matmul),
//                   32-col slice; writes l (split f16) / f_t,o_t (fp32).
//      WG 144..207: phase B = (16-row x 32-col) tile: u = tanh((l@W_a)*c+b_a),
//                   softmax over 8 channels, c/h update; c tile lives in LDS.
// ============================================================================

typedef _Float16 f16;
typedef _Float16 f16x8 __attribute__((ext_vector_type(8)));
typedef float    f32x4 __attribute__((ext_vector_type(4)));

#define DI static __device__ __forceinline__

constexpr int B_   = 64;
constexpr int H_   = 512;
constexpr int T_   = 1024;
constexpr int NWG  = 208;
constexpr int NTHR = 256;
constexpr int NA_WG = 144;   // 9 channel-pairs * 16 col slices

constexpr size_t MAT_ELE = (size_t)16 * 32 * 64 * 8;   // f16 elems per matrix blob

// ---- static device scratch (no ws dependence) ------------------------------
__device__ unsigned g_cnt;
__device__ f16   g_h1[B_ * H_];
__device__ f16   g_h2[B_ * H_];
__device__ float g_f [B_ * H_];
__device__ float g_o [B_ * H_];
__device__ f16   g_l1[8 * B_ * H_];
__device__ f16   g_l2[8 * B_ * H_];
__device__ f16   g_blob1[19 * MAT_ELE];   // hi parts
__device__ f16   g_blob2[19 * MAT_ELE];   // lo parts (pre-scaled x2048)

struct P {
  const float* Y;
  const float* x[7];
  const float *W_i, *U_i, *b_i, *W_f, *U_f, *b_f;
  const float *W_c, *U_c, *b_c, *W_o, *U_o, *b_o;
  const float *W_i_x, *U_i_x, *b_i_x, *W_c_x, *U_c_x, *b_c_x;
  const float *W_a, *b_a;
  float* out;   // [64*512] h_T, then [64,1024,512] hidden_seq
};

DI f32x4 mfma16(f16x8 a, f16x8 b, f32x4 c) {
  return __builtin_amdgcn_mfma_f32_16x16x32_f16(a, b, c, 0, 0, 0);
}

DI float sigmoidf_(float x) { return 1.0f / (1.0f + expf(-x)); }

// Monotone-counter device barrier (all NWG WGs call it equally often).
DI void gbar(unsigned target) {
  __syncthreads();
  if (threadIdx.x == 0) {
    __hip_atomic_fetch_add(&g_cnt, 1u, __ATOMIC_RELEASE, __HIP_MEMORY_SCOPE_AGENT);
    while (__hip_atomic_load(&g_cnt, __ATOMIC_RELAXED, __HIP_MEMORY_SCOPE_AGENT) < target) {
      __builtin_amdgcn_s_sleep(2);
    }
    __builtin_amdgcn_fence(__ATOMIC_ACQUIRE, "agent");
  }
  __syncthreads();
}

// ---------------------------------------------------------------------------
// Prep: zero counter + h state; swizzle 19 [512x512] fp32 matrices into
// split-f16 MFMA B-fragment blobs.
// mat ids: 0=U_i, 1..7=U_i_x[k], 8=U_f, 9=U_c, 10..16=U_c_x[k], 17=U_o, 18=W_a
// ---------------------------------------------------------------------------
__global__ void __launch_bounds__(256) prep_kernel(P p) {
  const int gid = blockIdx.x * blockDim.x + threadIdx.x;
  const int nth = gridDim.x * blockDim.x;
  if (gid == 0) g_cnt = 0u;
  {
    unsigned* z1 = (unsigned*)g_h1;
    unsigned* z2 = (unsigned*)g_h2;
    for (int i = gid; i < B_ * H_ / 2; i += nth) { z1[i] = 0u; z2[i] = 0u; }
  }
  const int lane = threadIdx.x & 63;
  const int wvg  = gid >> 6;
  const int nwv  = nth >> 6;
  for (int tile = wvg; tile < 19 * 16 * 32; tile += nwv) {
    const int mat = tile / (16 * 32);
    const int rem = tile % (16 * 32);
    const int kt = rem >> 5, nt = rem & 31;
    const float* src;
    if      (mat == 0)  src = p.U_i;
    else if (mat <  8)  src = p.U_i_x + (size_t)(mat - 1) * H_ * H_;
    else if (mat == 8)  src = p.U_f;
    else if (mat == 9)  src = p.U_c;
    else if (mat < 17)  src = p.U_c_x + (size_t)(mat - 10) * H_ * H_;
    else if (mat == 17) src = p.U_o;
    else                src = p.W_a;
    const int k0 = kt * 32 + (lane >> 4) * 8;     // B frag: k = quad*8+j
    const int n  = nt * 16 + (lane & 15);         //         n = lane&15
    f16x8 hv, lv;
#pragma unroll
    for (int j = 0; j < 8; ++j) {
      float v  = src[(size_t)(k0 + j) * H_ + n];
      f16   hh = (f16)v;
      hv[j] = hh;
      lv[j] = (f16)((v - (float)hh) * 2048.0f);   // lo pre-scaled by 2^11
    }
    size_t off = (size_t)mat * MAT_ELE + ((size_t)(kt * 32 + nt) * 64 + lane) * 8;
    *(f16x8*)(g_blob1 + off) = hv;
    *(f16x8*)(g_blob2 + off) = lv;
  }
}

// ---------------------------------------------------------------------------
// Main persistent kernel.
// ---------------------------------------------------------------------------
__global__ void __launch_bounds__(NTHR, 1) lstm_main(P p) {
  const int wg   = blockIdx.x;
  const int tid  = threadIdx.x;
  const int lane = tid & 63;
  const int wv   = tid >> 6;

  __shared__ float sInI[64][8];
  __shared__ float sInC[64][8];
  __shared__ float sWI[8][32];
  __shared__ float sWC[8][32];
  __shared__ float sbI[32];
  __shared__ float sbC[32];
  __shared__ float sba[32];
  __shared__ float c_lds[16][32];
  __shared__ float xch[4096];   // A: act exchange [2][64][32]; B: u [8][16][32]

  const bool isA = (wg < NA_WG);

  // ---- per-role setup -----------------------------------------------------
  int kap = 0, C0A = 0, KI = 8;
  const float* inI = p.Y;
  const float* inC = p.Y;
  int R0B = 0, C0B = 0;

  if (isA) {
    kap = wg >> 4;            // 0..8 channel pair
    C0A = (wg & 15) * 32;     // col slice
    KI  = (kap == 0 || kap == 8) ? 8 : 3;
    const float *WIs, *bIs, *WCs, *bCs;
    if (kap == 0)      { WIs = p.W_i; bIs = p.b_i; WCs = p.W_c; bCs = p.b_c; }
    else if (kap == 8) { WIs = p.W_f; bIs = p.b_f; WCs = p.W_o; bCs = p.b_o; }
    else {
      WIs = p.W_i_x + (size_t)(kap - 1) * 3 * H_;
      bIs = p.b_i_x + (size_t)(kap - 1) * H_;
      WCs = p.W_c_x + (size_t)(kap - 1) * 3 * H_;
      bCs = p.b_c_x + (size_t)(kap - 1) * H_;
      inI = (kap == 1) ? p.x[0] : p.x[1];   // xi = [x1, x2, x2, x2, x2, x2, x2]
      inC = p.x[kap - 1];                   // xc = [x1 .. x7]
    }
    for (int idx = tid; idx < KI * 32; idx += NTHR) {
      int i = idx >> 5, c = idx & 31;
      sWI[i][c] = WIs[(size_t)i * H_ + C0A + c];
      sWC[i][c] = WCs[(size_t)i * H_ + C0A + c];
    }
    if (tid < 32) { sbI[tid] = bIs[C0A + tid]; sbC[tid] = bCs[C0A + tid]; }
  } else {
    int w2 = wg - NA_WG;
    R0B = (w2 >> 4) * 16;     // batch-row tile
    C0B = (w2 & 15) * 32;     // col tile
    if (tid < 32) sba[tid] = p.b_a[C0B + tid];
    for (int idx = tid; idx < 512; idx += NTHR) c_lds[idx >> 5][idx & 31] = 0.0f;
  }
  __syncthreads();

  unsigned barno = 0;

  for (int t = 0; t < T_; ++t) {
    // ================= PHASE A ==========================================
    if (isA) {
      for (int idx = tid; idx < 64 * KI; idx += NTHR) {
        int b = idx / KI, i = idx % KI;
        sInI[b][i] = inI[((size_t)b * KI + i) * T_ + t];
        sInC[b][i] = inC[((size_t)b * KI + i) * T_ + t];
      }
      __syncthreads();

      const int mu  = wv >> 1;                  // 0 = i-type, 1 = c-type matrix
      const int mh  = wv & 1;                   // batch-row half (32 rows)
      const int mat = (mu == 0) ? kap : 9 + kap;
      const f16* bb1 = g_blob1 + (size_t)mat * MAT_ELE;
      const f16* bb2 = g_blob2 + (size_t)mat * MAT_ELE;

      f32x4 aH[2][2] = {};
      f32x4 aL[2][2] = {};
      const int koffl = (lane >> 4) * 8;
      const int mrow0 = mh * 32 + (lane & 15);
      const int nt0   = (C0A >> 4);             // first 16-col ntile

      for (int kt = 0; kt < 16; ++kt) {
        const int k0 = kt * 32 + koffl;
        f16x8 a1[2], a2[2];
#pragma unroll
        for (int mt = 0; mt < 2; ++mt) {
          size_t ho = (size_t)(mrow0 + mt * 16) * H_ + k0;
          a1[mt] = *(const f16x8*)(g_h1 + ho);
          a2[mt] = *(const f16x8*)(g_h2 + ho);
        }
#pragma unroll
        for (int nn = 0; nn < 2; ++nn) {
          size_t bo = ((size_t)(kt * 32 + nt0 + nn) * 64 + lane) * 8;
          f16x8 w1 = *(const f16x8*)(bb1 + bo);
          f16x8 w2 = *(const f16x8*)(bb2 + bo);
#pragma unroll
          for (int mt = 0; mt < 2; ++mt) {
            aH[mt][nn] = mfma16(a1[mt], w1, aH[mt][nn]);
            aL[mt][nn] = mfma16(a1[mt], w2, aL[mt][nn]);
            aL[mt][nn] = mfma16(a2[mt], w1, aL[mt][nn]);
          }
        }
      }

      // epilogue: input projection + bias + activation
#pragma unroll
      for (int mt = 0; mt < 2; ++mt) {
#pragma unroll
        for (int nn = 0; nn < 2; ++nn) {
#pragma unroll
          for (int r = 0; r < 4; ++r) {
            int b  = mh * 32 + mt * 16 + (lane >> 4) * 4 + r;
            int cl = nn * 16 + (lane & 15);
            float pre = aH[mt][nn][r] + aL[mt][nn][r] * (1.0f / 2048.0f);
            pre += mu ? sbC[cl] : sbI[cl];
            if (mu) { for (int i = 0; i < KI; ++i) pre += sInC[b][i] * sWC[i][cl]; }
            else    { for (int i = 0; i < KI; ++i) pre += sInI[b][i] * sWI[i][cl]; }
            if (kap == 8) {
              float g = sigmoidf_(pre);
              (mu ? g_o : g_f)[(size_t)b * H_ + C0A + cl] = g;   // f_t / o_t
            } else {
              float a = mu ? tanhf(pre) : sigmoidf_(pre);
              xch[mu * 2048 + b * 32 + cl] = a;
            }
          }
        }
      }
      if (kap != 8) {
        __syncthreads();
        for (int idx = tid; idx < 2048; idx += NTHR) {
          int b = idx >> 5, cl = idx & 31;
          float lv = xch[idx] * xch[2048 + idx];      // sigmoid(i) * tanh(c)
          f16 hi = (f16)lv;
          size_t o = ((size_t)kap * B_ + b) * H_ + C0A + cl;
          g_l1[o] = hi;
          g_l2[o] = (f16)((lv - (float)hi) * 2048.0f);
        }
      }
    }

    gbar((++barno) * (unsigned)NWG);

    // ================= PHASE B ==========================================
    if (!isA) {
      const int kp = wv * 2;          // this wave's two l-channels
      f32x4 aH[2][2] = {};
      f32x4 aL[2][2] = {};
      const int koffl = (lane >> 4) * 8;
      const int mrow  = R0B + (lane & 15);
      const f16* wb1 = g_blob1 + (size_t)18 * MAT_ELE;
      const f16* wb2 = g_blob2 + (size_t)18 * MAT_ELE;
      const int nt0  = (C0B >> 4);

      for (int kt = 0; kt < 16; ++kt) {
        const int k0 = kt * 32 + koffl;
        f16x8 a1[2], a2[2];
#pragma unroll
        for (int kk = 0; kk < 2; ++kk) {
          size_t o = ((size_t)(kp + kk) * B_ + mrow) * H_ + k0;
          a1[kk] = *(const f16x8*)(g_l1 + o);
          a2[kk] = *(const f16x8*)(g_l2 + o);
        }
#pragma unroll
        for (int nn = 0; nn < 2; ++nn) {
          size_t bo = ((size_t)(kt * 32 + nt0 + nn) * 64 + lane) * 8;
          f16x8 w1 = *(const f16x8*)(wb1 + bo);
          f16x8 w2 = *(const f16x8*)(wb2 + bo);
#pragma unroll
          for (int kk = 0; kk < 2; ++kk) {
            aH[kk][nn] = mfma16(a1[kk], w1, aH[kk][nn]);
            aL[kk][nn] = mfma16(a1[kk], w2, aL[kk][nn]);
            aL[kk][nn] = mfma16(a2[kk], w1, aL[kk][nn]);
          }
        }
      }

      // u = tanh((l @ W_a) * c_old + b_a) -> LDS
#pragma unroll
      for (int kk = 0; kk < 2; ++kk) {
#pragma unroll
        for (int nn = 0; nn < 2; ++nn) {
#pragma unroll
          for (int r = 0; r < 4; ++r) {
            int bl = (lane >> 4) * 4 + r;
            int cl = nn * 16 + (lane & 15);
            float dot = aH[kk][nn][r] + aL[kk][nn][r] * (1.0f / 2048.0f);
            float uv  = tanhf(dot * c_lds[bl][cl] + sba[cl]);
            xch[(kp + kk) * 512 + bl * 32 + cl] = uv;
          }
        }
      }
      __syncthreads();

      // softmax over 8 channels, L, c/h update, outputs
      for (int idx = tid; idx < 512; idx += NTHR) {
        int bl = idx >> 5, cl = idx & 31;
        int bg = R0B + bl, cgl = C0B + cl;
        float uv[8], um = -1e30f;
#pragma unroll
        for (int k = 0; k < 8; ++k) { uv[k] = xch[k * 512 + idx]; um = fmaxf(um, uv[k]); }
        float e[8], s = 0.0f;
#pragma unroll
        for (int k = 0; k < 8; ++k) { e[k] = expf(uv[k] - um); s += e[k]; }
        float inv = 1.0f / s;
        float L = 0.0f;
#pragma unroll
        for (int k = 0; k < 8; ++k) {
          size_t o = ((size_t)k * B_ + bg) * H_ + cgl;
          float lvv = (float)g_l1[o] + (float)g_l2[o] * (1.0f / 2048.0f);
          L += e[k] * inv * lvv;
        }
        float co = c_lds[bl][cl];
        float cn = g_f[(size_t)bg * H_ + cgl] * co + L;
        float hn = g_o[(size_t)bg * H_ + cgl] * tanhf(cn);
        c_lds[bl][cl] = cn;
        f16 hh = (f16)hn;
        g_h1[(size_t)bg * H_ + cgl] = hh;
        g_h2[(size_t)bg * H_ + cgl] = (f16)((hn - (float)hh) * 2048.0f);
        p.out[(size_t)B_ * H_ + ((size_t)bg * T_ + t) * H_ + cgl] = hn;
        if (t == T_ - 1) p.out[(size_t)bg * H_ + cgl] = hn;
      }
    }

    gbar((++barno) * (unsigned)NWG);
  }
}

// ---------------------------------------------------------------------------
extern "C" void kernel_launch(void* const* d_in, const int* in_sizes, int n_in,
                              void* d_out, int out_size, void* d_ws, size_t ws_size,
                              hipStream_t stream) {
  (void)in_sizes; (void)n_in; (void)out_size; (void)d_ws; (void)ws_size;

  P p;
  p.Y = (const float*)d_in[0];
  for (int i = 0; i < 7; ++i) p.x[i] = (const float*)d_in[1 + i];
  p.W_i   = (const float*)d_in[8];  p.U_i   = (const float*)d_in[9];  p.b_i   = (const float*)d_in[10];
  p.W_f   = (const float*)d_in[11]; p.U_f   = (const float*)d_in[12]; p.b_f   = (const float*)d_in[13];
  p.W_c   = (const float*)d_in[14]; p.U_c   = (const float*)d_in[15]; p.b_c   = (const float*)d_in[16];
  p.W_o   = (const float*)d_in[17]; p.U_o   = (const float*)d_in[18]; p.b_o   = (const float*)d_in[19];
  p.W_i_x = (const float*)d_in[20]; p.U_i_x = (const float*)d_in[21]; p.b_i_x = (const float*)d_in[22];
  p.W_c_x = (const float*)d_in[23]; p.U_c_x = (const float*)d_in[24]; p.b_c_x = (const float*)d_in[25];
  p.W_a   = (const float*)d_in[26]; p.b_a   = (const float*)d_in[27];
  p.out   = (float*)d_out;

  prep_kernel<<<dim3(256), dim3(256), 0, stream>>>(p);

  void* kargs[] = { (void*)&p };
  hipError_t err = hipLaunchCooperativeKernel((void*)lstm_main, dim3(NWG), dim3(NTHR),
                                              kargs, 0, stream);
  if (err != hipSuccess) {
    // Fallback: plain launch. 208 blocks x 24.9 KB LDS -> <=6 blocks/CU, so
    // all 208 are co-resident on 256 CUs; custom barrier needs only that.
    lstm_main<<<dim3(NWG), dim3(NTHR), 0, stream>>>(p);
  }
}

// Round 3
// 45776.379 us; speedup vs baseline: 1.3882x; 1.3882x over previous
//
#include <hip/hip_runtime.h>

// ============================================================================
// CustomMultiInputLSTM (B=64, H=512, T=1024, 7 aux) on gfx950 — round 3.
//
// Round 2 passed (absmax 1.2e-4) at 63.5 ms, but MfmaUtil 1.76% / VALUBusy
// 2.3% => ~58 of 62 us/step was the flat single-cacheline atomic barrier
// (208 serialized RMWs ~= 30 us/barrier) + post-fence re-fetch of 19 MB/step
// of weights (FETCH_SIZE 8.3 GB/launch).
//
// Round 3 changes:
//  * Two-level broadcast barrier: per-WG arrival slots (no contention),
//    master WG polls all 208 slots in parallel (lanes 0..207), publishes one
//    epoch word. ~1-2 us vs ~30 us.
//  * Weights live in LDS (gfx950: 160 KB/WG). A-WG: its 2 matrix slices =
//    128 KB; B-WG: W_a slice = 64 KB. K-loop weight reads are ds_read_b128,
//    immune to the per-step L1/L2 invalidation.
//  * 512-thread WGs: K dimension split across wave pairs (kh=0/1), partial
//    sums combined through LDS; 2 waves/SIMD for latency hiding; depth-1
//    software prefetch of the h/l A-fragments (global, LLC-resident).
//  * Numerics unchanged: split-f16 (hi + lo/2048), 3 MFMAs per frag pair,
//    fp32 accumulate.
// ============================================================================

typedef _Float16 f16;
typedef _Float16 f16x8 __attribute__((ext_vector_type(8)));
typedef float    f32x4 __attribute__((ext_vector_type(4)));

#define DI static __device__ __forceinline__

constexpr int B_   = 64;
constexpr int H_   = 512;
constexpr int T_   = 1024;
constexpr int NWG  = 208;
constexpr int NTHR = 512;
constexpr int NA_WG = 144;   // 9 channel-pairs * 16 col slices

constexpr size_t MAT_ELE = (size_t)16 * 32 * 64 * 8;   // f16 elems per matrix blob

// ---- LDS pool layout (single static array, role-dependent use) -------------
constexpr int OFF_W    = 0;          // A: 2 mats * 64KB ; B: W_a 64KB
constexpr int OFF_U    = 65536;      // B only: u[8][16][32] f32 (16 KB)
constexpr int OFF_RED  = 131072;     // 4 slots * 4KB partial sums; A reuses as act[2][64][32]
constexpr int OFF_SINI = 147456;     // [64][8] f32
constexpr int OFF_SINC = 149504;
constexpr int OFF_SWI  = 151552;     // [8][32] f32
constexpr int OFF_SWC  = 152576;
constexpr int OFF_SBI  = 153600;     // 3 * 32 f32
constexpr int OFF_SBC  = 153728;
constexpr int OFF_SBA  = 153856;
constexpr int OFF_CLDS = 153984;     // [16][32] f32
constexpr int POOL_SZ  = 156032;     // <= 163840

// ---- static device scratch -------------------------------------------------
__device__ unsigned g_arrive[256];
__device__ unsigned g_epoch;
__device__ f16   g_h1[B_ * H_];
__device__ f16   g_h2[B_ * H_];
__device__ float g_f [B_ * H_];
__device__ float g_o [B_ * H_];
__device__ f16   g_l1[8 * B_ * H_];
__device__ f16   g_l2[8 * B_ * H_];
__device__ f16   g_blob1[19 * MAT_ELE];   // hi parts
__device__ f16   g_blob2[19 * MAT_ELE];   // lo parts (pre-scaled x2048)

struct P {
  const float* Y;
  const float* x[7];
  const float *W_i, *U_i, *b_i, *W_f, *U_f, *b_f;
  const float *W_c, *U_c, *b_c, *W_o, *U_o, *b_o;
  const float *W_i_x, *U_i_x, *b_i_x, *W_c_x, *U_c_x, *b_c_x;
  const float *W_a, *b_a;
  float* out;   // [64*512] h_T, then [64,1024,512] hidden_seq
};

DI f32x4 mfma16(f16x8 a, f16x8 b, f32x4 c) {
  return __builtin_amdgcn_mfma_f32_16x16x32_f16(a, b, c, 0, 0, 0);
}
DI float sigmoidf_(float x) { return 1.0f / (1.0f + expf(-x)); }

// Two-level broadcast barrier. epoch is monotone (1,2,3,...).
DI void gbar(unsigned epoch, int wg, int tid) {
  __syncthreads();
  if (tid == 0)
    __hip_atomic_store(&g_arrive[wg], epoch, __ATOMIC_RELEASE, __HIP_MEMORY_SCOPE_AGENT);
  if (wg == 0) {
    if (tid < NWG) {
      while (__hip_atomic_load(&g_arrive[tid], __ATOMIC_RELAXED, __HIP_MEMORY_SCOPE_AGENT) < epoch)
        __builtin_amdgcn_s_sleep(1);
    }
    __syncthreads();
    if (tid == 0) {
      __builtin_amdgcn_fence(__ATOMIC_ACQUIRE, "agent");
      __hip_atomic_store(&g_epoch, epoch, __ATOMIC_RELEASE, __HIP_MEMORY_SCOPE_AGENT);
    }
  } else {
    if (tid == 0) {
      while (__hip_atomic_load(&g_epoch, __ATOMIC_RELAXED, __HIP_MEMORY_SCOPE_AGENT) < epoch)
        __builtin_amdgcn_s_sleep(1);
      __builtin_amdgcn_fence(__ATOMIC_ACQUIRE, "agent");
    }
  }
  __syncthreads();
}

// ---------------------------------------------------------------------------
// Prep: zero barrier state + h; swizzle 19 [512x512] fp32 matrices into
// split-f16 MFMA B-fragment blobs.
// mat ids: 0=U_i, 1..7=U_i_x[k], 8=U_f, 9=U_c, 10..16=U_c_x[k], 17=U_o, 18=W_a
// ---------------------------------------------------------------------------
__global__ void __launch_bounds__(256) prep_kernel(P p) {
  const int gid = blockIdx.x * blockDim.x + threadIdx.x;
  const int nth = gridDim.x * blockDim.x;
  if (gid == 0) g_epoch = 0u;
  if (gid < 256) g_arrive[gid] = 0u;
  {
    unsigned* z1 = (unsigned*)g_h1;
    unsigned* z2 = (unsigned*)g_h2;
    for (int i = gid; i < B_ * H_ / 2; i += nth) { z1[i] = 0u; z2[i] = 0u; }
  }
  const int lane = threadIdx.x & 63;
  const int wvg  = gid >> 6;
  const int nwv  = nth >> 6;
  for (int tile = wvg; tile < 19 * 16 * 32; tile += nwv) {
    const int mat = tile / (16 * 32);
    const int rem = tile % (16 * 32);
    const int kt = rem >> 5, nt = rem & 31;
    const float* src;
    if      (mat == 0)  src = p.U_i;
    else if (mat <  8)  src = p.U_i_x + (size_t)(mat - 1) * H_ * H_;
    else if (mat == 8)  src = p.U_f;
    else if (mat == 9)  src = p.U_c;
    else if (mat < 17)  src = p.U_c_x + (size_t)(mat - 10) * H_ * H_;
    else if (mat == 17) src = p.U_o;
    else                src = p.W_a;
    const int k0 = kt * 32 + (lane >> 4) * 8;     // B frag: k = quad*8+j
    const int n  = nt * 16 + (lane & 15);         //         n = lane&15
    f16x8 hv, lv;
#pragma unroll
    for (int j = 0; j < 8; ++j) {
      float v  = src[(size_t)(k0 + j) * H_ + n];
      f16   hh = (f16)v;
      hv[j] = hh;
      lv[j] = (f16)((v - (float)hh) * 2048.0f);
    }
    size_t off = (size_t)mat * MAT_ELE + ((size_t)(kt * 32 + nt) * 64 + lane) * 8;
    *(f16x8*)(g_blob1 + off) = hv;
    *(f16x8*)(g_blob2 + off) = lv;
  }
}

// ---------------------------------------------------------------------------
// Main persistent kernel: 512 threads (8 waves).
//   A-WG waves: mu = wv>>2 (i-type / c-type matrix), mh = (wv>>1)&1 (32-row
//               half), kh = wv&1 (K half, 8 kt each).
//   B-WG waves: chPair = wv>>1 (2 l-channels), kh = wv&1.
// ---------------------------------------------------------------------------
__global__ void __launch_bounds__(NTHR, 1) lstm_main(P p) {
  const int wg   = blockIdx.x;
  const int tid  = threadIdx.x;
  const int lane = tid & 63;
  const int wv   = tid >> 6;

  __shared__ __align__(16) char pool[POOL_SZ];
  float* sInI = (float*)(pool + OFF_SINI);
  float* sInC = (float*)(pool + OFF_SINC);
  float* sWI  = (float*)(pool + OFF_SWI);
  float* sWC  = (float*)(pool + OFF_SWC);
  float* sbI  = (float*)(pool + OFF_SBI);
  float* sbC  = (float*)(pool + OFF_SBC);
  float* sba  = (float*)(pool + OFF_SBA);
  float* cl_  = (float*)(pool + OFF_CLDS);
  float* redf = (float*)(pool + OFF_RED);
  float* uf   = (float*)(pool + OFF_U);

  const bool isA = (wg < NA_WG);

  // ---- per-role setup -----------------------------------------------------
  int kap = 0, C0A = 0, KI = 8, nt0 = 0;
  const float* inI = p.Y;
  const float* inC = p.Y;
  int R0B = 0, C0B = 0;

  if (isA) {
    kap = wg >> 4;
    C0A = (wg & 15) * 32;
    nt0 = C0A >> 4;
    KI  = (kap == 0 || kap == 8) ? 8 : 3;
    const float *WIs, *bIs, *WCs, *bCs;
    if (kap == 0)      { WIs = p.W_i; bIs = p.b_i; WCs = p.W_c; bCs = p.b_c; }
    else if (kap == 8) { WIs = p.W_f; bIs = p.b_f; WCs = p.W_o; bCs = p.b_o; }
    else {
      WIs = p.W_i_x + (size_t)(kap - 1) * 3 * H_;
      bIs = p.b_i_x + (size_t)(kap - 1) * H_;
      WCs = p.W_c_x + (size_t)(kap - 1) * 3 * H_;
      bCs = p.b_c_x + (size_t)(kap - 1) * H_;
      inI = (kap == 1) ? p.x[0] : p.x[1];   // xi = [x1, x2, x2, x2, x2, x2, x2]
      inC = p.x[kap - 1];                   // xc = [x1 .. x7]
    }
    for (int idx = tid; idx < KI * 32; idx += NTHR) {
      int i = idx >> 5, c = idx & 31;
      sWI[i * 32 + c] = WIs[(size_t)i * H_ + C0A + c];
      sWC[i * 32 + c] = WCs[(size_t)i * H_ + C0A + c];
    }
    if (tid < 32) { sbI[tid] = bIs[C0A + tid]; sbC[tid] = bCs[C0A + tid]; }
    // weight slices -> LDS: frag = mu*64 + kt*4 + nn*2 + half (128 frags x 1KB)
    for (int c = tid; c < 8192; c += NTHR) {
      int frag = c >> 6, ln = c & 63;
      int half = frag & 1, nn = (frag >> 1) & 1, kt = (frag >> 2) & 15, mu = frag >> 6;
      int mat = mu ? (9 + kap) : kap;
      size_t so = (size_t)mat * MAT_ELE + ((size_t)(kt * 32 + nt0 + nn) * 64 + ln) * 8;
      const f16* src = half ? g_blob2 : g_blob1;
      *(f16x8*)(pool + OFF_W + (size_t)frag * 1024 + ln * 16) = *(const f16x8*)(src + so);
    }
  } else {
    int w2 = wg - NA_WG;
    R0B = (w2 >> 4) * 16;
    C0B = (w2 & 15) * 32;
    nt0 = C0B >> 4;
    if (tid < 32) sba[tid] = p.b_a[C0B + tid];
    for (int idx = tid; idx < 512; idx += NTHR) cl_[idx] = 0.0f;
    // W_a slice -> LDS: frag = kt*4 + nn*2 + half (64 frags x 1KB)
    for (int c = tid; c < 4096; c += NTHR) {
      int frag = c >> 6, ln = c & 63;
      int half = frag & 1, nn = (frag >> 1) & 1, kt = frag >> 2;
      size_t so = (size_t)18 * MAT_ELE + ((size_t)(kt * 32 + nt0 + nn) * 64 + ln) * 8;
      const f16* src = half ? g_blob2 : g_blob1;
      *(f16x8*)(pool + OFF_W + (size_t)frag * 1024 + ln * 16) = *(const f16x8*)(src + so);
    }
  }
  __syncthreads();

  const int quad  = lane >> 4;
  const int l15   = lane & 15;
  const int koffl = quad * 8;
  const int kh    = wv & 1;
  unsigned barno = 0;

  for (int t = 0; t < T_; ++t) {
    // ================= PHASE A ==========================================
    if (isA) {
      for (int idx = tid; idx < 64 * KI; idx += NTHR) {
        int b = idx / KI, i = idx % KI;
        sInI[b * 8 + i] = inI[((size_t)b * KI + i) * T_ + t];
        sInC[b * 8 + i] = inC[((size_t)b * KI + i) * T_ + t];
      }

      const int mu = wv >> 2;
      const int mh = (wv >> 1) & 1;
      const int slot = mu * 2 + mh;
      const int mrow0 = mh * 32 + l15;
      const int ktBase = kh * 8;

      f32x4 aH[2][2] = {};
      f32x4 aL[2][2] = {};
      f16x8 c1[2], c2[2], n1[2], n2[2];
      {
        int k0 = ktBase * 32 + koffl;
#pragma unroll
        for (int mt = 0; mt < 2; ++mt) {
          size_t ho = (size_t)(mrow0 + mt * 16) * H_ + k0;
          c1[mt] = *(const f16x8*)(g_h1 + ho);
          c2[mt] = *(const f16x8*)(g_h2 + ho);
        }
      }
      for (int i = 0; i < 8; ++i) {
        const int kt = ktBase + i;
        if (i < 7) {
          int k0 = (kt + 1) * 32 + koffl;
#pragma unroll
          for (int mt = 0; mt < 2; ++mt) {
            size_t ho = (size_t)(mrow0 + mt * 16) * H_ + k0;
            n1[mt] = *(const f16x8*)(g_h1 + ho);
            n2[mt] = *(const f16x8*)(g_h2 + ho);
          }
        }
#pragma unroll
        for (int nn = 0; nn < 2; ++nn) {
          int f = ((mu * 16 + kt) * 2 + nn) * 2;
          f16x8 w1 = *(const f16x8*)(pool + OFF_W + (size_t)f * 1024 + lane * 16);
          f16x8 w2 = *(const f16x8*)(pool + OFF_W + (size_t)(f + 1) * 1024 + lane * 16);
#pragma unroll
          for (int mt = 0; mt < 2; ++mt) {
            aH[mt][nn] = mfma16(c1[mt], w1, aH[mt][nn]);
            aL[mt][nn] = mfma16(c1[mt], w2, aL[mt][nn]);
            aL[mt][nn] = mfma16(c2[mt], w1, aL[mt][nn]);
          }
        }
        if (i < 7) {
#pragma unroll
          for (int mt = 0; mt < 2; ++mt) { c1[mt] = n1[mt]; c2[mt] = n2[mt]; }
        }
      }

      // K-half reduction through LDS
      if (kh == 1) {
#pragma unroll
        for (int mt = 0; mt < 2; ++mt)
#pragma unroll
          for (int nn = 0; nn < 2; ++nn) {
            f32x4 comb = aH[mt][nn] + aL[mt][nn] * (1.0f / 2048.0f);
            *(f32x4*)(redf + slot * 1024 + ((mt * 2 + nn) * 64 + lane) * 4) = comb;
          }
      }
      __syncthreads();

      float actv[2][2][4];
      if (kh == 0) {
#pragma unroll
        for (int mt = 0; mt < 2; ++mt)
#pragma unroll
          for (int nn = 0; nn < 2; ++nn) {
            f32x4 other = *(const f32x4*)(redf + slot * 1024 + ((mt * 2 + nn) * 64 + lane) * 4);
            f32x4 mine  = aH[mt][nn] + aL[mt][nn] * (1.0f / 2048.0f) + other;
#pragma unroll
            for (int r = 0; r < 4; ++r) {
              int b  = mh * 32 + mt * 16 + quad * 4 + r;
              int cc = nn * 16 + l15;
              float pre = mine[r] + (mu ? sbC[cc] : sbI[cc]);
              const float* si = mu ? sInC : sInI;
              const float* sw = mu ? sWC  : sWI;
              for (int i = 0; i < KI; ++i) pre += si[b * 8 + i] * sw[i * 32 + cc];
              if (kap == 8) {
                (mu ? g_o : g_f)[(size_t)b * H_ + C0A + cc] = sigmoidf_(pre);
              } else {
                actv[mt][nn][r] = mu ? tanhf(pre) : sigmoidf_(pre);
              }
            }
          }
      }
      __syncthreads();
      if (kap != 8) {
        if (kh == 0) {
#pragma unroll
          for (int mt = 0; mt < 2; ++mt)
#pragma unroll
            for (int nn = 0; nn < 2; ++nn)
#pragma unroll
              for (int r = 0; r < 4; ++r) {
                int b  = mh * 32 + mt * 16 + quad * 4 + r;
                int cc = nn * 16 + l15;
                redf[mu * 2048 + b * 32 + cc] = actv[mt][nn][r];
              }
        }
        __syncthreads();
        for (int idx = tid; idx < 2048; idx += NTHR) {
          int b = idx >> 5, cc = idx & 31;
          float lv = redf[idx] * redf[2048 + idx];     // sigmoid(i) * tanh(c~)
          f16 hi = (f16)lv;
          size_t o = ((size_t)kap * B_ + b) * H_ + C0A + cc;
          g_l1[o] = hi;
          g_l2[o] = (f16)((lv - (float)hi) * 2048.0f);
        }
      } else {
        __syncthreads();   // keep per-WG barrier count uniform across waves
      }
    }

    gbar(++barno, wg, tid);

    // ================= PHASE B ==========================================
    if (!isA) {
      const int chPair = wv >> 1;
      const int kp = chPair * 2;
      const int mrow = R0B + l15;
      const int ktBase = kh * 8;

      f32x4 aH[2][2] = {};
      f32x4 aL[2][2] = {};
      f16x8 c1[2], c2[2], n1[2], n2[2];
      {
        int k0 = ktBase * 32 + koffl;
#pragma unroll
        for (int kk = 0; kk < 2; ++kk) {
          size_t o = ((size_t)(kp + kk) * B_ + mrow) * H_ + k0;
          c1[kk] = *(const f16x8*)(g_l1 + o);
          c2[kk] = *(const f16x8*)(g_l2 + o);
        }
      }
      for (int i = 0; i < 8; ++i) {
        const int kt = ktBase + i;
        if (i < 7) {
          int k0 = (kt + 1) * 32 + koffl;
#pragma unroll
          for (int kk = 0; kk < 2; ++kk) {
            size_t o = ((size_t)(kp + kk) * B_ + mrow) * H_ + k0;
            n1[kk] = *(const f16x8*)(g_l1 + o);
            n2[kk] = *(const f16x8*)(g_l2 + o);
          }
        }
#pragma unroll
        for (int nn = 0; nn < 2; ++nn) {
          int f = (kt * 2 + nn) * 2;
          f16x8 w1 = *(const f16x8*)(pool + OFF_W + (size_t)f * 1024 + lane * 16);
          f16x8 w2 = *(const f16x8*)(pool + OFF_W + (size_t)(f + 1) * 1024 + lane * 16);
#pragma unroll
          for (int kk = 0; kk < 2; ++kk) {
            aH[kk][nn] = mfma16(c1[kk], w1, aH[kk][nn]);
            aL[kk][nn] = mfma16(c1[kk], w2, aL[kk][nn]);
            aL[kk][nn] = mfma16(c2[kk], w1, aL[kk][nn]);
          }
        }
        if (i < 7) {
#pragma unroll
          for (int kk = 0; kk < 2; ++kk) { c1[kk] = n1[kk]; c2[kk] = n2[kk]; }
        }
      }

      if (kh == 1) {
#pragma unroll
        for (int kk = 0; kk < 2; ++kk)
#pragma unroll
          for (int nn = 0; nn < 2; ++nn) {
            f32x4 comb = aH[kk][nn] + aL[kk][nn] * (1.0f / 2048.0f);
            *(f32x4*)(redf + chPair * 1024 + ((kk * 2 + nn) * 64 + lane) * 4) = comb;
          }
      }
      __syncthreads();
      if (kh == 0) {
#pragma unroll
        for (int kk = 0; kk < 2; ++kk)
#pragma unroll
          for (int nn = 0; nn < 2; ++nn) {
            f32x4 other = *(const f32x4*)(redf + chPair * 1024 + ((kk * 2 + nn) * 64 + lane) * 4);
            f32x4 dot   = aH[kk][nn] + aL[kk][nn] * (1.0f / 2048.0f) + other;
#pragma unroll
            for (int r = 0; r < 4; ++r) {
              int bl = quad * 4 + r;
              int cc = nn * 16 + l15;
              float uv = tanhf(dot[r] * cl_[bl * 32 + cc] + sba[cc]);
              uf[(kp + kk) * 512 + bl * 32 + cc] = uv;
            }
          }
      }
      __syncthreads();

      // softmax over 8 channels, L, c/h update, outputs (512 thr, 1 elem each)
      {
        int idx = tid;
        int bl = idx >> 5, cc = idx & 31;
        int bg = R0B + bl, cgl = C0B + cc;
        float uv[8], um = -1e30f;
#pragma unroll
        for (int k = 0; k < 8; ++k) { uv[k] = uf[k * 512 + idx]; um = fmaxf(um, uv[k]); }
        float e[8], s = 0.0f;
#pragma unroll
        for (int k = 0; k < 8; ++k) { e[k] = expf(uv[k] - um); s += e[k]; }
        float inv = 1.0f / s;
        float L = 0.0f;
#pragma unroll
        for (int k = 0; k < 8; ++k) {
          size_t o = ((size_t)k * B_ + bg) * H_ + cgl;
          float lvv = (float)g_l1[o] + (float)g_l2[o] * (1.0f / 2048.0f);
          L += e[k] * inv * lvv;
        }
        float co = cl_[bl * 32 + cc];
        float cn = g_f[(size_t)bg * H_ + cgl] * co + L;
        float hn = g_o[(size_t)bg * H_ + cgl] * tanhf(cn);
        cl_[bl * 32 + cc] = cn;
        f16 hh = (f16)hn;
        g_h1[(size_t)bg * H_ + cgl] = hh;
        g_h2[(size_t)bg * H_ + cgl] = (f16)((hn - (float)hh) * 2048.0f);
        p.out[(size_t)B_ * H_ + ((size_t)bg * T_ + t) * H_ + cgl] = hn;
        if (t == T_ - 1) p.out[(size_t)bg * H_ + cgl] = hn;
      }
    }

    gbar(++barno, wg, tid);
  }
}

// ---------------------------------------------------------------------------
extern "C" void kernel_launch(void* const* d_in, const int* in_sizes, int n_in,
                              void* d_out, int out_size, void* d_ws, size_t ws_size,
                              hipStream_t stream) {
  (void)in_sizes; (void)n_in; (void)out_size; (void)d_ws; (void)ws_size;

  P p;
  p.Y = (const float*)d_in[0];
  for (int i = 0; i < 7; ++i) p.x[i] = (const float*)d_in[1 + i];
  p.W_i   = (const float*)d_in[8];  p.U_i   = (const float*)d_in[9];  p.b_i   = (const float*)d_in[10];
  p.W_f   = (const float*)d_in[11]; p.U_f   = (const float*)d_in[12]; p.b_f   = (const float*)d_in[13];
  p.W_c   = (const float*)d_in[14]; p.U_c   = (const float*)d_in[15]; p.b_c   = (const float*)d_in[16];
  p.W_o   = (const float*)d_in[17]; p.U_o   = (const float*)d_in[18]; p.b_o   = (const float*)d_in[19];
  p.W_i_x = (const float*)d_in[20]; p.U_i_x = (const float*)d_in[21]; p.b_i_x = (const float*)d_in[22];
  p.W_c_x = (const float*)d_in[23]; p.U_c_x = (const float*)d_in[24]; p.b_c_x = (const float*)d_in[25];
  p.W_a   = (const float*)d_in[26]; p.b_a   = (const float*)d_in[27];
  p.out   = (float*)d_out;

  prep_kernel<<<dim3(256), dim3(256), 0, stream>>>(p);

  void* kargs[] = { (void*)&p };
  hipError_t err = hipLaunchCooperativeKernel((void*)lstm_main, dim3(NWG), dim3(NTHR),
                                              kargs, 0, stream);
  if (err != hipSuccess) {
    // Fallback: plain launch. 208 blocks, 1/CU (LDS-bound) on 256 CUs => all
    // co-resident; the custom barrier only needs co-residency.
    lstm_main<<<dim3(NWG), dim3(NTHR), 0, stream>>>(p);
  }
}